// Round 9
// baseline (570.255 us; speedup 1.0000x reference)
//
#include <hip/hip_runtime.h>

// ResidualAttentionBlock on MI355X (gfx950).
// D=768 H=12 HD=64 NQ=100 KV=257 SEQ=357 BS=32.
// Round 9: A/B test — fc GEMM uses DIRECT fragment loads from global (no LDS, no barriers,
// pure register pipeline); proj keeps the R8 LDS structure as the control. XCD A-slice
// mapping (R8, FETCH-verified) kept for both. Attention unchanged.

typedef short bf16x8 __attribute__((ext_vector_type(8)));
typedef float f32x4 __attribute__((ext_vector_type(4)));
typedef unsigned short u16;
typedef unsigned long long u64;

__device__ __forceinline__ u16 f2b(float f) {
    unsigned u = __builtin_bit_cast(unsigned, f);
    u = (u + 0x7fffu + ((u >> 16) & 1u)) >> 16;  // RNE
    return (u16)u;
}
__device__ __forceinline__ float b2f(u16 h) {
    unsigned u = ((unsigned)h) << 16;
    return __builtin_bit_cast(float, u);
}
__device__ __forceinline__ unsigned pack2(float a, float b) {
    return (unsigned)f2b(a) | ((unsigned)f2b(b) << 16);
}
// async global->LDS, 16B per lane; LDS dest = wave-uniform base + lane*16
__device__ __forceinline__ void g2l16(const void* g, void* l) {
    __builtin_amdgcn_global_load_lds(
        (__attribute__((address_space(1))) void*)g,
        (__attribute__((address_space(3))) void*)l, 16, 0, 0);
}
#define MFMA16(a, b, c) __builtin_amdgcn_mfma_f32_16x16x32_bf16((a), (b), (c), 0, 0, 0)

// ---------------- fused f32 -> bf16 conversion of all 5 weights ----------------
__global__ __launch_bounds__(256) void cvt5_kernel(
    const float* __restrict__ s0, const float* __restrict__ s1, const float* __restrict__ s2,
    const float* __restrict__ s3, const float* __restrict__ s4, u16* __restrict__ dst)
{
    int i = blockIdx.x * 256 + threadIdx.x;
    int stride = gridDim.x * 256;
    for (; i < 1916928; i += stride) {
        const float* src; int off;
        if (i < 442368)       { src = s0; off = i; }
        else if (i < 589824)  { src = s1; off = i - 442368; }
        else if (i < 737280)  { src = s2; off = i - 589824; }
        else if (i < 1327104) { src = s3; off = i - 737280; }
        else                  { src = s4; off = i - 1327104; }
        float4 v = ((const float4*)src)[off];
        ushort4 o;
        o.x = f2b(v.x); o.y = f2b(v.y); o.z = f2b(v.z); o.w = f2b(v.w);
        ((ushort4*)dst)[i] = o;
    }
}

// ---------------- mask -> packed bitmask [32*100][5] u64 ----------------
__global__ __launch_bounds__(256) void mask_pack(const int* __restrict__ m, u64* __restrict__ o) {
    int row = blockIdx.x * 4 + (threadIdx.x >> 6);
    int lane = threadIdx.x & 63;
    if (row >= 3200) return;
    const int* r = m + (size_t)row * 257;
    u64 w0 = __ballot(r[lane] != 0);
    u64 w1 = __ballot(r[64 + lane] != 0);
    u64 w2 = __ballot(r[128 + lane] != 0);
    u64 w3 = __ballot(r[192 + lane] != 0);
    u64 w4 = __ballot(lane == 0 && r[256] != 0);
    if (lane == 0) {
        u64* p = o + (size_t)row * 5;
        p[0] = w0; p[1] = w1; p[2] = w2; p[3] = w3; p[4] = w4;
    }
}

// ---------------- LayerNorm (fp32 in, bf16 out), one wave per row of 768 ----------------
__global__ __launch_bounds__(256) void ln_kernel(
    const float* __restrict__ in, const float* __restrict__ g, const float* __restrict__ be,
    u16* __restrict__ out, int nrows)
{
    int row = blockIdx.x * 4 + (threadIdx.x >> 6);
    int lane = threadIdx.x & 63;
    if (row >= nrows) return;
    const float* p = in + (size_t)row * 768;
    float4 a0 = *(const float4*)(p + lane * 4);
    float4 a1 = *(const float4*)(p + 256 + lane * 4);
    float4 a2 = *(const float4*)(p + 512 + lane * 4);
    float s = a0.x + a0.y + a0.z + a0.w + a1.x + a1.y + a1.z + a1.w + a2.x + a2.y + a2.z + a2.w;
    for (int o = 32; o; o >>= 1) s += __shfl_xor(s, o);
    float mean = s * (1.f / 768.f);
    float vs = 0.f;
#define SQA(t) { float dx; dx = t.x-mean; vs += dx*dx; dx = t.y-mean; vs += dx*dx; dx = t.z-mean; vs += dx*dx; dx = t.w-mean; vs += dx*dx; }
    SQA(a0) SQA(a1) SQA(a2)
#undef SQA
    for (int o = 32; o; o >>= 1) vs += __shfl_xor(vs, o);
    float rstd = rsqrtf(vs * (1.f / 768.f) + 1e-5f);
    u16* orow = out + (size_t)row * 768;
#pragma unroll
    for (int i = 0; i < 3; ++i) {
        int d = i * 256 + lane * 4;
        float4 av = (i == 0) ? a0 : ((i == 1) ? a1 : a2);
        float4 gv = *(const float4*)(g + d);
        float4 bv = *(const float4*)(be + d);
        ushort4 ov;
        ov.x = f2b((av.x - mean) * rstd * gv.x + bv.x);
        ov.y = f2b((av.y - mean) * rstd * gv.y + bv.y);
        ov.z = f2b((av.z - mean) * rstd * gv.z + bv.z);
        ov.w = f2b((av.w - mean) * rstd * gv.w + bv.w);
        *(ushort4*)(orow + d) = ov;
    }
}

// ---------------- bf16 MFMA GEMM: C[M][N] = A[M][K] @ B[N][K]^T + bias (+res) ----------------
// 128x128 tile, 4 waves (2x2), 4x4 16x16 frags/wave, BK=32.
// DIRECT=0: R8 structure — 2-buffer LDS via global_load_lds, one barrier per K-step.
// DIRECT=1: NO LDS / NO barriers — each lane loads its MFMA fragment straight from
//           global (16B at row(+fr)*K + k0 + fg*8); 1-tile-ahead register pipeline;
//           compiler inserts counted vmcnt automatically (G7).
// XCD mapping (both): gridDim.x padded to x8; XCD k owns M-tile slice, column-inner order.
template<int ACT, int OUTBF, int RES, int DIRECT>
__global__ __launch_bounds__(256) void gemm_bt(
    const u16* __restrict__ A, const u16* __restrict__ B,
    const float* __restrict__ bias, const float* __restrict__ res,
    void* __restrict__ Cp, int M, int N, int K)
{
    const int t = threadIdx.x;
    const int lane = t & 63, w = t >> 6;
    const int wr = w >> 1, wc = w & 1;
    const int fr = lane & 15, fg = lane >> 4;

    const int raw = blockIdx.x + gridDim.x * blockIdx.y;
    const int rows_per = gridDim.x >> 3;          // gridDim.x % 8 == 0
    const int gy = gridDim.y;
    const int xcd = raw & 7, idx = raw >> 3;
    const int nt = idx % gy;
    const int mt = xcd * rows_per + idx / gy;
    const int m0 = mt * 128, n0 = nt * 128;
    if (m0 >= M) return;                          // padded tail block (uniform exit, pre-barrier)

    const int nk = K >> 5;
    f32x4 acc[4][4] = {};

    if constexpr (DIRECT) {
        // per-lane fragment base pointers (row-clamped)
        const u16* ap[4];
        const u16* bp[4];
#pragma unroll
        for (int m = 0; m < 4; ++m) {
            int r = m0 + wr * 64 + m * 16 + fr;
            r = r < M ? r : M - 1;
            ap[m] = A + (size_t)r * K + fg * 8;
        }
#pragma unroll
        for (int n = 0; n < 4; ++n) {
            int r = n0 + wc * 64 + n * 16 + fr;   // N tiles never padded (N%128==0)
            bp[n] = B + (size_t)r * K + fg * 8;
        }
        bf16x8 a0[4], b0[4], a1[4], b1[4];
        auto loadset = [&](bf16x8* aa, bf16x8* bb, int k0) {
#pragma unroll
            for (int m = 0; m < 4; ++m) aa[m] = *(const bf16x8*)(ap[m] + k0);
#pragma unroll
            for (int n = 0; n < 4; ++n) bb[n] = *(const bf16x8*)(bp[n] + k0);
        };
        auto mfmaset = [&](const bf16x8* aa, const bf16x8* bb) {
#pragma unroll
            for (int m = 0; m < 4; ++m)
#pragma unroll
                for (int n = 0; n < 4; ++n)
                    acc[m][n] = MFMA16(aa[m], bb[n], acc[m][n]);
        };
        loadset(a0, b0, 0);
#pragma unroll 1
        for (int ki = 0; ki < nk; ki += 2) {      // nk even for all shapes here (24 or 96)
            if (ki + 1 < nk) loadset(a1, b1, (ki + 1) << 5);
            mfmaset(a0, b0);
            if (ki + 2 < nk) loadset(a0, b0, (ki + 2) << 5);
            if (ki + 1 < nk) mfmaset(a1, b1);
        }
    } else {
        __shared__ u16 Al[2][128 * 32];
        __shared__ u16 Bl[2][128 * 32];
        // staging: wave w covers rows w*32..+31 (2 instrs x 16 rows); lane l -> row +(l>>2),
        // 16B slot (l&3). LDS dest wave-uniform base + lane*16; global src per-lane (clamped).
        const int srow = lane >> 2;
        const int scol = (lane & 3) * 8;
        int ar0 = m0 + w * 32 + srow;      int ar1 = ar0 + 16;
        ar0 = ar0 < M ? ar0 : M - 1;       ar1 = ar1 < M ? ar1 : M - 1;
        int br0 = n0 + w * 32 + srow;      int br1 = br0 + 16;
        br0 = br0 < N ? br0 : N - 1;       br1 = br1 < N ? br1 : N - 1;
        const u16* a0p = A + (size_t)ar0 * K + scol;
        const u16* a1p = A + (size_t)ar1 * K + scol;
        const u16* b0p = B + (size_t)br0 * K + scol;
        const u16* b1p = B + (size_t)br1 * K + scol;
        const int lo0 = (w * 2 + 0) * 512, lo1 = (w * 2 + 1) * 512;

        g2l16(a0p, &Al[0][lo0]);
        g2l16(a1p, &Al[0][lo1]);
        g2l16(b0p, &Bl[0][lo0]);
        g2l16(b1p, &Bl[0][lo1]);
        __syncthreads();

#pragma unroll 2
        for (int ki = 0; ki < nk; ++ki) {
            const int cur = ki & 1;
            if (ki + 1 < nk) {
                const int k0 = (ki + 1) << 5;
                const int nxt = cur ^ 1;
                g2l16(a0p + k0, &Al[nxt][lo0]);
                g2l16(a1p + k0, &Al[nxt][lo1]);
                g2l16(b0p + k0, &Bl[nxt][lo0]);
                g2l16(b1p + k0, &Bl[nxt][lo1]);
            }
            bf16x8 af[4], bfr[4];
#pragma unroll
            for (int m = 0; m < 4; ++m) af[m] = *(const bf16x8*)&Al[cur][(wr * 64 + m * 16 + fr) * 32 + fg * 8];
#pragma unroll
            for (int n = 0; n < 4; ++n) bfr[n] = *(const bf16x8*)&Bl[cur][(wc * 64 + n * 16 + fr) * 32 + fg * 8];
#pragma unroll
            for (int m = 0; m < 4; ++m)
#pragma unroll
                for (int n = 0; n < 4; ++n)
                    acc[m][n] = MFMA16(af[m], bfr[n], acc[m][n]);
            __syncthreads();
        }
    }
    // Epilogue. C/D layout: col = lane&15, row = (lane>>4)*4 + r  [measured m89/m91]
#pragma unroll
    for (int m = 0; m < 4; ++m) {
#pragma unroll
        for (int n = 0; n < 4; ++n) {
            int col = n0 + wc * 64 + n * 16 + fr;
            float bv = bias[col];
#pragma unroll
            for (int r = 0; r < 4; ++r) {
                int row = m0 + wr * 64 + m * 16 + fg * 4 + r;
                if (row < M) {
                    float v = acc[m][n][r] + bv;
                    if (RES) v += res[(size_t)row * N + col];
                    if (ACT) v = v / (1.f + __expf(-1.702f * v));  // QuickGELU
                    if (OUTBF) ((u16*)Cp)[(size_t)row * N + col] = f2b(v);
                    else       ((float*)Cp)[(size_t)row * N + col] = v;
                }
            }
        }
    }
}

// ---------------- MFMA attention: one block per (b,h) ----------------
// XCD swizzle: each XCD's 48 blocks contiguous = 4 complete batches -> K/V L2-local.
__global__ __launch_bounds__(256, 2) void attn_kernel(
    const u16* __restrict__ qkv,   // [257*32][2304] rows m*32+b; q|k|v at +0/+768/+1536
    const u16* __restrict__ nq,    // [100*32][768]  rows q*32+b
    const u64* __restrict__ mpk,   // [32*100][5] packed mask bits (1 = blocked)
    u16* __restrict__ out)         // [357*32][768]  rows q*32+b
{
    __shared__ u16 Kl[272 * 64];   // K rows, XOR-swizzled: byte ^= (row&7)<<4
    __shared__ u16 Vt[64 * 296];   // Vt[d][m], row stride 592B
    __shared__ u16 Pb[4][640];     // per-wave P chunk buffer [16][40]
    const int raw = blockIdx.x;
    const int bid = (raw & 7) * 48 + (raw >> 3);   // 384 = 8 XCDs x 48 contiguous
    const int b = bid / 12, h = bid % 12;
    const int t = threadIdx.x, lane = t & 63, wv = t >> 6;
    const int fr = lane & 15, fg = lane >> 4;

    for (int i = t; i < 2048; i += 256) {
        int d = i >> 5, c = 257 + (i & 31);
        if (c < 288) Vt[d * 296 + c] = 0;
    }
    {
        const int r8 = t >> 3, c8 = (t & 7) * 8;
        const u16* kb = qkv + 768 + h * 64 + c8;
        const u16* vb = qkv + 1536 + h * 64 + c8;
#pragma unroll 1
        for (int p = 0; p < 9; ++p) {
            int m = r8 + p * 32;
            if (m <= 256) {
                size_t go = (size_t)(m * 32 + b) * 2304;
                bf16x8 kv = *(const bf16x8*)(kb + go);
                int byte = m * 128 + c8 * 2;
                *(bf16x8*)((char*)Kl + (byte ^ ((m & 7) << 4))) = kv;
                bf16x8 vv = *(const bf16x8*)(vb + go);
#pragma unroll
                for (int j = 0; j < 8; ++j)
                    Vt[(c8 + j) * 296 + m] = (u16)vv[j];
            }
        }
    }
    __syncthreads();

    const int swzK = (fr & 7) << 4;
    char* pb = (char*)&Pb[wv][0];
    const char* KlB = (const char*)Kl;
    const char* VtB = (const char*)Vt;

    auto fetch = [&](int ti, bf16x8& q0v, bf16x8& q1v, u64* mw, bool& im) {
        int q = ti * 16 + fr;
        int qc = q < 357 ? q : 356;
        im = qc < 100;
        const u16* qp = im ? (nq + (size_t)(qc * 32 + b) * 768 + h * 64)
                           : (qkv + (size_t)((qc - 100) * 32 + b) * 2304 + h * 64);
        q0v = *(const bf16x8*)(qp + fg * 8);
        q1v = *(const bf16x8*)(qp + 32 + fg * 8);
        if (im) {
            const u64* mp = mpk + (size_t)(b * 100 + qc) * 5;
            mw[0] = mp[0]; mw[1] = mp[1]; mw[2] = mp[2]; mw[3] = mp[3]; mw[4] = mp[4];
        } else {
            mw[0] = mw[1] = mw[2] = mw[3] = mw[4] = 0;
        }
    };

    bf16x8 qf0, qf1, qn0, qn1;
    u64 mwc[5], mwn[5];
    bool imc, imn;
    fetch(wv, qf0, qf1, mwc, imc);

#pragma unroll 1
    for (int ti = wv; ti < 23; ti += 4) {
        f32x4 sc[17];
#pragma unroll
        for (int kt = 0; kt < 17; ++kt) {
            int rb = (kt * 16 + fr) * 128;
            bf16x8 ka0 = *(const bf16x8*)(KlB + ((rb + fg * 16) ^ swzK));
            bf16x8 ka1 = *(const bf16x8*)(KlB + ((rb + 64 + fg * 16) ^ swzK));
            f32x4 a = {0.f, 0.f, 0.f, 0.f};
            a = MFMA16(ka0, qf0, a);
            a = MFMA16(ka1, qf1, a);
            sc[kt] = a;
        }
        if (ti + 4 < 23) fetch(ti + 4, qn0, qn1, mwn, imn);
        float mx = -INFINITY;
#pragma unroll
        for (int kt = 0; kt < 17; ++kt) {
            u64 mw = (kt >> 2) == 0 ? mwc[0] : (kt >> 2) == 1 ? mwc[1] : (kt >> 2) == 2 ? mwc[2]
                   : (kt >> 2) == 3 ? mwc[3] : mwc[4];
#pragma unroll
            for (int r = 0; r < 4; ++r) {
                int key = kt * 16 + fg * 4 + r;
                bool bad = (key > 256) || (imc && ((mw >> (key & 63)) & 1ull));
                float s = bad ? -INFINITY : sc[kt][r];
                sc[kt][r] = s;
                mx = fmaxf(mx, s);
            }
        }
        mx = fmaxf(mx, __shfl_xor(mx, 16));
        mx = fmaxf(mx, __shfl_xor(mx, 32));
        float l = 0.f;
        unsigned pk[17][2];
#pragma unroll
        for (int kt = 0; kt < 17; ++kt) {
            float p0 = __expf((sc[kt][0] - mx) * 0.125f);
            float p1 = __expf((sc[kt][1] - mx) * 0.125f);
            float p2 = __expf((sc[kt][2] - mx) * 0.125f);
            float p3 = __expf((sc[kt][3] - mx) * 0.125f);
            l += (p0 + p1) + (p2 + p3);
            pk[kt][0] = pack2(p0, p1);
            pk[kt][1] = pack2(p2, p3);
        }
        l += __shfl_xor(l, 16);
        l += __shfl_xor(l, 32);
        f32x4 oc[4] = {};
#pragma unroll
        for (int c = 0; c < 9; ++c) {
            uint2 w0; w0.x = pk[2 * c][0]; w0.y = pk[2 * c][1];
            *(uint2*)(pb + fr * 80 + fg * 8) = w0;
            uint2 w1;
            if (c < 8) { w1.x = pk[2 * c + 1][0]; w1.y = pk[2 * c + 1][1]; }
            else       { w1.x = 0; w1.y = 0; }
            *(uint2*)(pb + fr * 80 + 32 + fg * 8) = w1;
            bf16x8 pf = *(const bf16x8*)(pb + fr * 80 + fg * 16);
#pragma unroll
            for (int dt = 0; dt < 4; ++dt) {
                bf16x8 vf = *(const bf16x8*)(VtB + (dt * 16 + fr) * 592 + c * 64 + fg * 16);
                oc[dt] = MFMA16(vf, pf, oc[dt]);
            }
        }
        int q = ti * 16 + fr;
        if (q < 357) {
            float rl = 1.f / l;
            u16* op = out + (size_t)(q * 32 + b) * 768 + h * 64 + fg * 4;
#pragma unroll
            for (int dt = 0; dt < 4; ++dt) {
                ushort4 ov;
                ov.x = f2b(oc[dt][0] * rl); ov.y = f2b(oc[dt][1] * rl);
                ov.z = f2b(oc[dt][2] * rl); ov.w = f2b(oc[dt][3] * rl);
                *(ushort4*)(op + dt * 16) = ov;
            }
        }
        if (ti + 4 < 23) {
            qf0 = qn0; qf1 = qn1; imc = imn;
            mwc[0] = mwn[0]; mwc[1] = mwn[1]; mwc[2] = mwn[2]; mwc[3] = mwn[3]; mwc[4] = mwn[4];
        }
    }
}

// ---------------- launch ----------------
extern "C" void kernel_launch(void* const* d_in, const int* in_sizes, int n_in,
                              void* d_out, int out_size, void* d_ws, size_t ws_size,
                              hipStream_t stream)
{
    const float* y   = (const float*)d_in[0];
    const int*   msk = (const int*)  d_in[1];
    const float* ipw = (const float*)d_in[2];
    const float* ipb = (const float*)d_in[3];
    const float* nqw = (const float*)d_in[4];
    const float* nqb = (const float*)d_in[5];
    const float* ow  = (const float*)d_in[6];
    const float* ob  = (const float*)d_in[7];
    const float* l1g = (const float*)d_in[8];
    const float* l1b = (const float*)d_in[9];
    const float* l2g = (const float*)d_in[10];
    const float* l2b = (const float*)d_in[11];
    const float* fcw = (const float*)d_in[12];
    const float* fcb = (const float*)d_in[13];
    const float* pjw = (const float*)d_in[14];
    const float* pjb = (const float*)d_in[15];

    char* ws = (char*)d_ws;
    u16* x_b   = (u16*)(ws + 0);          // 11424 x 768
    u16* qkv_b = (u16*)(ws + 17547264);   //  8224 x 2304
    u16* nq_b  = (u16*)(ws + 55443456);   //  3200 x 768
    u16* ao_b  = (u16*)(ws + 60358656);   // 11424 x 768
    u16* h1_b  = (u16*)(ws + 0);          // 11424 x 3072 (phase 2, overlaps phase-1 region)
    u16* h_b   = (u16*)(ws + 77905920);   // 11424 x 768 (phase 2)
    u64* mpk_b = (u64*)(ws + 77905920);   // 3200 x 5 u64 (phase 1 only)
    u16* w_ip  = (u16*)(ws + 95453184);   // weights contiguous: ip|nq|out|fc|pj
    float* out = (float*)d_out;

    cvt5_kernel<<<2048, 256, 0, stream>>>(ipw, nqw, ow, fcw, pjw, w_ip);
    mask_pack<<<800, 256, 0, stream>>>(msk, mpk_b);

    u16* w_nq  = w_ip + 1769472;
    u16* w_out = w_nq + 589824;
    u16* w_fc  = w_out + 589824;
    u16* w_pj  = w_fc + 2359296;

    // x = LN1(y) -> bf16
    ln_kernel<<<2856, 256, 0, stream>>>(y, l1g, l1b, x_b, 11424);
    // qkv = x[100:] @ in_proj_w.T + b   (LDS variant)
    gemm_bt<0, 1, 0, 0><<<dim3(72, 18), 256, 0, stream>>>(x_b + (size_t)3200 * 768, w_ip, ipb, nullptr, qkv_b, 8224, 2304, 768);
    // new_q = x[:100] @ new_q_w.T + b   (LDS variant)
    gemm_bt<0, 1, 0, 0><<<dim3(32, 6), 256, 0, stream>>>(x_b, w_nq, nqb, nullptr, nq_b, 3200, 768, 768);
    // attention
    attn_kernel<<<384, 256, 0, stream>>>(qkv_b, nq_b, mpk_b, ao_b);
    // y2 = y + attn_out @ out_w.T + out_b   -> d_out (f32)   (LDS variant)
    gemm_bt<0, 0, 1, 0><<<dim3(96, 6), 256, 0, stream>>>(ao_b, w_out, ob, y, out, 11424, 768, 768);
    // h = LN2(y2) -> bf16
    ln_kernel<<<2856, 256, 0, stream>>>(out, l2g, l2b, h_b, 11424);
    // h1 = quickgelu(h @ fc_w.T + fc_b) -> bf16   *** DIRECT variant (A/B test) ***
    gemm_bt<1, 1, 0, 1><<<dim3(96, 24), 256, 0, stream>>>(h_b, w_fc, fcb, nullptr, h1_b, 11424, 3072, 768);
    // out = y2 + h1 @ proj_w.T + proj_b   (LDS control, equal FLOP to fc)
    gemm_bt<0, 0, 1, 0><<<dim3(96, 6), 256, 0, stream>>>(h1_b, w_pj, pjb, out, out, 11424, 768, 3072);
}

// Round 10
// 459.858 us; speedup vs baseline: 1.2401x; 1.2401x over previous
//
#include <hip/hip_runtime.h>

// ResidualAttentionBlock on MI355X (gfx950).
// D=768 H=12 HD=64 NQ=100 KV=257 SEQ=357 BS=32.
// Round 10: revert fc to LDS GEMM (R9 A/B: DIRECT 237us vs LDS 110us — TA scatter-bound).
// attn -> 512 threads / 8 waves per (b,h): 3 q-tiles per wave instead of 6, same staging;
// LDS trimmed to exactly 80KB so 2 blocks/CU survive.

typedef short bf16x8 __attribute__((ext_vector_type(8)));
typedef float f32x4 __attribute__((ext_vector_type(4)));
typedef unsigned short u16;
typedef unsigned long long u64;

__device__ __forceinline__ u16 f2b(float f) {
    unsigned u = __builtin_bit_cast(unsigned, f);
    u = (u + 0x7fffu + ((u >> 16) & 1u)) >> 16;  // RNE
    return (u16)u;
}
__device__ __forceinline__ float b2f(u16 h) {
    unsigned u = ((unsigned)h) << 16;
    return __builtin_bit_cast(float, u);
}
__device__ __forceinline__ unsigned pack2(float a, float b) {
    return (unsigned)f2b(a) | ((unsigned)f2b(b) << 16);
}
// async global->LDS, 16B per lane; LDS dest = wave-uniform base + lane*16
__device__ __forceinline__ void g2l16(const void* g, void* l) {
    __builtin_amdgcn_global_load_lds(
        (__attribute__((address_space(1))) void*)g,
        (__attribute__((address_space(3))) void*)l, 16, 0, 0);
}
#define MFMA16(a, b, c) __builtin_amdgcn_mfma_f32_16x16x32_bf16((a), (b), (c), 0, 0, 0)

// ---------------- fused f32 -> bf16 conversion of all 5 weights ----------------
__global__ __launch_bounds__(256) void cvt5_kernel(
    const float* __restrict__ s0, const float* __restrict__ s1, const float* __restrict__ s2,
    const float* __restrict__ s3, const float* __restrict__ s4, u16* __restrict__ dst)
{
    int i = blockIdx.x * 256 + threadIdx.x;
    int stride = gridDim.x * 256;
    for (; i < 1916928; i += stride) {
        const float* src; int off;
        if (i < 442368)       { src = s0; off = i; }
        else if (i < 589824)  { src = s1; off = i - 442368; }
        else if (i < 737280)  { src = s2; off = i - 589824; }
        else if (i < 1327104) { src = s3; off = i - 737280; }
        else                  { src = s4; off = i - 1327104; }
        float4 v = ((const float4*)src)[off];
        ushort4 o;
        o.x = f2b(v.x); o.y = f2b(v.y); o.z = f2b(v.z); o.w = f2b(v.w);
        ((ushort4*)dst)[i] = o;
    }
}

// ---------------- mask -> packed bitmask [32*100][5] u64 ----------------
__global__ __launch_bounds__(256) void mask_pack(const int* __restrict__ m, u64* __restrict__ o) {
    int row = blockIdx.x * 4 + (threadIdx.x >> 6);
    int lane = threadIdx.x & 63;
    if (row >= 3200) return;
    const int* r = m + (size_t)row * 257;
    u64 w0 = __ballot(r[lane] != 0);
    u64 w1 = __ballot(r[64 + lane] != 0);
    u64 w2 = __ballot(r[128 + lane] != 0);
    u64 w3 = __ballot(r[192 + lane] != 0);
    u64 w4 = __ballot(lane == 0 && r[256] != 0);
    if (lane == 0) {
        u64* p = o + (size_t)row * 5;
        p[0] = w0; p[1] = w1; p[2] = w2; p[3] = w3; p[4] = w4;
    }
}

// ---------------- LayerNorm (fp32 in, bf16 out), one wave per row of 768 ----------------
__global__ __launch_bounds__(256) void ln_kernel(
    const float* __restrict__ in, const float* __restrict__ g, const float* __restrict__ be,
    u16* __restrict__ out, int nrows)
{
    int row = blockIdx.x * 4 + (threadIdx.x >> 6);
    int lane = threadIdx.x & 63;
    if (row >= nrows) return;
    const float* p = in + (size_t)row * 768;
    float4 a0 = *(const float4*)(p + lane * 4);
    float4 a1 = *(const float4*)(p + 256 + lane * 4);
    float4 a2 = *(const float4*)(p + 512 + lane * 4);
    float s = a0.x + a0.y + a0.z + a0.w + a1.x + a1.y + a1.z + a1.w + a2.x + a2.y + a2.z + a2.w;
    for (int o = 32; o; o >>= 1) s += __shfl_xor(s, o);
    float mean = s * (1.f / 768.f);
    float vs = 0.f;
#define SQA(t) { float dx; dx = t.x-mean; vs += dx*dx; dx = t.y-mean; vs += dx*dx; dx = t.z-mean; vs += dx*dx; dx = t.w-mean; vs += dx*dx; }
    SQA(a0) SQA(a1) SQA(a2)
#undef SQA
    for (int o = 32; o; o >>= 1) vs += __shfl_xor(vs, o);
    float rstd = rsqrtf(vs * (1.f / 768.f) + 1e-5f);
    u16* orow = out + (size_t)row * 768;
#pragma unroll
    for (int i = 0; i < 3; ++i) {
        int d = i * 256 + lane * 4;
        float4 av = (i == 0) ? a0 : ((i == 1) ? a1 : a2);
        float4 gv = *(const float4*)(g + d);
        float4 bv = *(const float4*)(be + d);
        ushort4 ov;
        ov.x = f2b((av.x - mean) * rstd * gv.x + bv.x);
        ov.y = f2b((av.y - mean) * rstd * gv.y + bv.y);
        ov.z = f2b((av.z - mean) * rstd * gv.z + bv.z);
        ov.w = f2b((av.w - mean) * rstd * gv.w + bv.w);
        *(ushort4*)(orow + d) = ov;
    }
}

// ---------------- bf16 MFMA GEMM: C[M][N] = A[M][K] @ B[N][K]^T + bias (+res) ----------------
// 128x128 tile, 4 waves (2x2), 4x4 16x16 frags/wave, BK=32.
// 2-buffer LDS, prefetch-ahead staging, one barrier per K-step (R4/R8 structure — best measured).
// XCD mapping: gridDim.x padded to x8; XCD k owns M-tile slice, column-inner order.
template<int ACT, int OUTBF, int RES>
__global__ __launch_bounds__(256) void gemm_bt(
    const u16* __restrict__ A, const u16* __restrict__ B,
    const float* __restrict__ bias, const float* __restrict__ res,
    void* __restrict__ Cp, int M, int N, int K)
{
    __shared__ u16 Al[2][128 * 32];
    __shared__ u16 Bl[2][128 * 32];
    const int t = threadIdx.x;
    const int lane = t & 63, w = t >> 6;
    const int wr = w >> 1, wc = w & 1;
    const int fr = lane & 15, fg = lane >> 4;

    const int raw = blockIdx.x + gridDim.x * blockIdx.y;
    const int rows_per = gridDim.x >> 3;          // gridDim.x % 8 == 0
    const int gy = gridDim.y;
    const int xcd = raw & 7, idx = raw >> 3;
    const int nt = idx % gy;
    const int mt = xcd * rows_per + idx / gy;
    const int m0 = mt * 128, n0 = nt * 128;
    if (m0 >= M) return;                          // padded tail block (uniform exit, pre-barrier)

    const int srow = lane >> 2;
    const int scol = (lane & 3) * 8;
    int ar0 = m0 + w * 32 + srow;      int ar1 = ar0 + 16;
    ar0 = ar0 < M ? ar0 : M - 1;       ar1 = ar1 < M ? ar1 : M - 1;
    int br0 = n0 + w * 32 + srow;      int br1 = br0 + 16;
    br0 = br0 < N ? br0 : N - 1;       br1 = br1 < N ? br1 : N - 1;
    const u16* a0p = A + (size_t)ar0 * K + scol;
    const u16* a1p = A + (size_t)ar1 * K + scol;
    const u16* b0p = B + (size_t)br0 * K + scol;
    const u16* b1p = B + (size_t)br1 * K + scol;
    const int lo0 = (w * 2 + 0) * 512, lo1 = (w * 2 + 1) * 512;

    const int nk = K >> 5;
    g2l16(a0p, &Al[0][lo0]);
    g2l16(a1p, &Al[0][lo1]);
    g2l16(b0p, &Bl[0][lo0]);
    g2l16(b1p, &Bl[0][lo1]);
    __syncthreads();

    f32x4 acc[4][4] = {};
#pragma unroll 2
    for (int ki = 0; ki < nk; ++ki) {
        const int cur = ki & 1;
        if (ki + 1 < nk) {               // issue next-tile loads BEFORE compute
            const int k0 = (ki + 1) << 5;
            const int nxt = cur ^ 1;
            g2l16(a0p + k0, &Al[nxt][lo0]);
            g2l16(a1p + k0, &Al[nxt][lo1]);
            g2l16(b0p + k0, &Bl[nxt][lo0]);
            g2l16(b1p + k0, &Bl[nxt][lo1]);
        }
        bf16x8 af[4], bfr[4];
#pragma unroll
        for (int m = 0; m < 4; ++m) af[m] = *(const bf16x8*)&Al[cur][(wr * 64 + m * 16 + fr) * 32 + fg * 8];
#pragma unroll
        for (int n = 0; n < 4; ++n) bfr[n] = *(const bf16x8*)&Bl[cur][(wc * 64 + n * 16 + fr) * 32 + fg * 8];
#pragma unroll
        for (int m = 0; m < 4; ++m)
#pragma unroll
            for (int n = 0; n < 4; ++n)
                acc[m][n] = MFMA16(af[m], bfr[n], acc[m][n]);
        __syncthreads();  // drains this wave's vmcnt(0) (next-tile loads) + barrier
    }
    // Epilogue. C/D layout: col = lane&15, row = (lane>>4)*4 + r  [measured m89/m91]
#pragma unroll
    for (int m = 0; m < 4; ++m) {
#pragma unroll
        for (int n = 0; n < 4; ++n) {
            int col = n0 + wc * 64 + n * 16 + fr;
            float bv = bias[col];
#pragma unroll
            for (int r = 0; r < 4; ++r) {
                int row = m0 + wr * 64 + m * 16 + fg * 4 + r;
                if (row < M) {
                    float v = acc[m][n][r] + bv;
                    if (RES) v += res[(size_t)row * N + col];
                    if (ACT) v = v / (1.f + __expf(-1.702f * v));  // QuickGELU
                    if (OUTBF) ((u16*)Cp)[(size_t)row * N + col] = f2b(v);
                    else       ((float*)Cp)[(size_t)row * N + col] = v;
                }
            }
        }
    }
}

// ---------------- MFMA attention: one block per (b,h), 512 threads / 8 waves ----------------
// 8 waves share the 23 q-tiles (3/wave vs 6 at 4 waves) -> half the per-block critical path.
// LDS exactly 80KB: Kl 264 rows (reads of rows 257..271 land in-block, values masked),
// Vt [64][296], Pb[8]. 2 blocks/CU.
__global__ __launch_bounds__(512) void attn_kernel(
    const u16* __restrict__ qkv,   // [257*32][2304] rows m*32+b; q|k|v at +0/+768/+1536
    const u16* __restrict__ nq,    // [100*32][768]  rows q*32+b
    const u64* __restrict__ mpk,   // [32*100][5] packed mask bits (1 = blocked)
    u16* __restrict__ out)         // [357*32][768]  rows q*32+b
{
    __shared__ u16 Kl[264 * 64];   // K rows, XOR-swizzled: byte ^= (row&7)<<4  (33792 B)
    __shared__ u16 Vt[64 * 296];   // Vt[d][m], row stride 592B                 (37888 B)
    __shared__ u16 Pb[8][640];     // per-wave P chunk buffer [16][40]          (10240 B)
    const int raw = blockIdx.x;
    const int bid = (raw & 7) * 48 + (raw >> 3);   // 384 = 8 XCDs x 48 contiguous
    const int b = bid / 12, h = bid % 12;
    const int t = threadIdx.x, lane = t & 63, wv = t >> 6;
    const int fr = lane & 15, fg = lane >> 4;

    for (int i = t; i < 2048; i += 512) {
        int d = i >> 5, c = 257 + (i & 31);
        if (c < 288) Vt[d * 296 + c] = 0;
    }
    {
        const int r8 = t >> 3, c8 = (t & 7) * 8;   // 64 rows per pass at 512 threads
        const u16* kb = qkv + 768 + h * 64 + c8;
        const u16* vb = qkv + 1536 + h * 64 + c8;
#pragma unroll 1
        for (int p = 0; p < 5; ++p) {
            int m = r8 + p * 64;
            if (m <= 256) {
                size_t go = (size_t)(m * 32 + b) * 2304;
                bf16x8 kv = *(const bf16x8*)(kb + go);
                int byte = m * 128 + c8 * 2;
                *(bf16x8*)((char*)Kl + (byte ^ ((m & 7) << 4))) = kv;
                bf16x8 vv = *(const bf16x8*)(vb + go);
#pragma unroll
                for (int j = 0; j < 8; ++j)
                    Vt[(c8 + j) * 296 + m] = (u16)vv[j];
            }
        }
    }
    __syncthreads();

    const int swzK = (fr & 7) << 4;
    char* pb = (char*)&Pb[wv][0];
    const char* KlB = (const char*)Kl;
    const char* VtB = (const char*)Vt;

    auto fetch = [&](int ti, bf16x8& q0v, bf16x8& q1v, u64* mw, bool& im) {
        int q = ti * 16 + fr;
        int qc = q < 357 ? q : 356;
        im = qc < 100;
        const u16* qp = im ? (nq + (size_t)(qc * 32 + b) * 768 + h * 64)
                           : (qkv + (size_t)((qc - 100) * 32 + b) * 2304 + h * 64);
        q0v = *(const bf16x8*)(qp + fg * 8);
        q1v = *(const bf16x8*)(qp + 32 + fg * 8);
        if (im) {
            const u64* mp = mpk + (size_t)(b * 100 + qc) * 5;
            mw[0] = mp[0]; mw[1] = mp[1]; mw[2] = mp[2]; mw[3] = mp[3]; mw[4] = mp[4];
        } else {
            mw[0] = mw[1] = mw[2] = mw[3] = mw[4] = 0;
        }
    };

    bf16x8 qf0, qf1, qn0, qn1;
    u64 mwc[5], mwn[5];
    bool imc, imn;
    fetch(wv, qf0, qf1, mwc, imc);

#pragma unroll 1
    for (int ti = wv; ti < 23; ti += 8) {
        f32x4 sc[17];
#pragma unroll
        for (int kt = 0; kt < 17; ++kt) {
            int rb = (kt * 16 + fr) * 128;
            bf16x8 ka0 = *(const bf16x8*)(KlB + ((rb + fg * 16) ^ swzK));
            bf16x8 ka1 = *(const bf16x8*)(KlB + ((rb + 64 + fg * 16) ^ swzK));
            f32x4 a = {0.f, 0.f, 0.f, 0.f};
            a = MFMA16(ka0, qf0, a);
            a = MFMA16(ka1, qf1, a);
            sc[kt] = a;
        }
        if (ti + 8 < 23) fetch(ti + 8, qn0, qn1, mwn, imn);
        float mx = -INFINITY;
#pragma unroll
        for (int kt = 0; kt < 17; ++kt) {
            u64 mw = (kt >> 2) == 0 ? mwc[0] : (kt >> 2) == 1 ? mwc[1] : (kt >> 2) == 2 ? mwc[2]
                   : (kt >> 2) == 3 ? mwc[3] : mwc[4];
#pragma unroll
            for (int r = 0; r < 4; ++r) {
                int key = kt * 16 + fg * 4 + r;
                bool bad = (key > 256) || (imc && ((mw >> (key & 63)) & 1ull));
                float s = bad ? -INFINITY : sc[kt][r];
                sc[kt][r] = s;
                mx = fmaxf(mx, s);
            }
        }
        mx = fmaxf(mx, __shfl_xor(mx, 16));
        mx = fmaxf(mx, __shfl_xor(mx, 32));
        float l = 0.f;
        unsigned pk[17][2];
#pragma unroll
        for (int kt = 0; kt < 17; ++kt) {
            float p0 = __expf((sc[kt][0] - mx) * 0.125f);
            float p1 = __expf((sc[kt][1] - mx) * 0.125f);
            float p2 = __expf((sc[kt][2] - mx) * 0.125f);
            float p3 = __expf((sc[kt][3] - mx) * 0.125f);
            l += (p0 + p1) + (p2 + p3);
            pk[kt][0] = pack2(p0, p1);
            pk[kt][1] = pack2(p2, p3);
        }
        l += __shfl_xor(l, 16);
        l += __shfl_xor(l, 32);
        f32x4 oc[4] = {};
#pragma unroll
        for (int c = 0; c < 9; ++c) {
            uint2 w0; w0.x = pk[2 * c][0]; w0.y = pk[2 * c][1];
            *(uint2*)(pb + fr * 80 + fg * 8) = w0;
            uint2 w1;
            if (c < 8) { w1.x = pk[2 * c + 1][0]; w1.y = pk[2 * c + 1][1]; }
            else       { w1.x = 0; w1.y = 0; }
            *(uint2*)(pb + fr * 80 + 32 + fg * 8) = w1;
            bf16x8 pf = *(const bf16x8*)(pb + fr * 80 + fg * 16);
#pragma unroll
            for (int dt = 0; dt < 4; ++dt) {
                bf16x8 vf = *(const bf16x8*)(VtB + (dt * 16 + fr) * 592 + c * 64 + fg * 16);
                oc[dt] = MFMA16(vf, pf, oc[dt]);
            }
        }
        int q = ti * 16 + fr;
        if (q < 357) {
            float rl = 1.f / l;
            u16* op = out + (size_t)(q * 32 + b) * 768 + h * 64 + fg * 4;
#pragma unroll
            for (int dt = 0; dt < 4; ++dt) {
                ushort4 ov;
                ov.x = f2b(oc[dt][0] * rl); ov.y = f2b(oc[dt][1] * rl);
                ov.z = f2b(oc[dt][2] * rl); ov.w = f2b(oc[dt][3] * rl);
                *(ushort4*)(op + dt * 16) = ov;
            }
        }
        if (ti + 8 < 23) {
            qf0 = qn0; qf1 = qn1; imc = imn;
            mwc[0] = mwn[0]; mwc[1] = mwn[1]; mwc[2] = mwn[2]; mwc[3] = mwn[3]; mwc[4] = mwn[4];
        }
    }
}

// ---------------- launch ----------------
extern "C" void kernel_launch(void* const* d_in, const int* in_sizes, int n_in,
                              void* d_out, int out_size, void* d_ws, size_t ws_size,
                              hipStream_t stream)
{
    const float* y   = (const float*)d_in[0];
    const int*   msk = (const int*)  d_in[1];
    const float* ipw = (const float*)d_in[2];
    const float* ipb = (const float*)d_in[3];
    const float* nqw = (const float*)d_in[4];
    const float* nqb = (const float*)d_in[5];
    const float* ow  = (const float*)d_in[6];
    const float* ob  = (const float*)d_in[7];
    const float* l1g = (const float*)d_in[8];
    const float* l1b = (const float*)d_in[9];
    const float* l2g = (const float*)d_in[10];
    const float* l2b = (const float*)d_in[11];
    const float* fcw = (const float*)d_in[12];
    const float* fcb = (const float*)d_in[13];
    const float* pjw = (const float*)d_in[14];
    const float* pjb = (const float*)d_in[15];

    char* ws = (char*)d_ws;
    u16* x_b   = (u16*)(ws + 0);          // 11424 x 768
    u16* qkv_b = (u16*)(ws + 17547264);   //  8224 x 2304
    u16* nq_b  = (u16*)(ws + 55443456);   //  3200 x 768
    u16* ao_b  = (u16*)(ws + 60358656);   // 11424 x 768
    u16* h1_b  = (u16*)(ws + 0);          // 11424 x 3072 (phase 2, overlaps phase-1 region)
    u16* h_b   = (u16*)(ws + 77905920);   // 11424 x 768 (phase 2)
    u64* mpk_b = (u64*)(ws + 77905920);   // 3200 x 5 u64 (phase 1 only)
    u16* w_ip  = (u16*)(ws + 95453184);   // weights contiguous: ip|nq|out|fc|pj
    float* out = (float*)d_out;

    cvt5_kernel<<<2048, 256, 0, stream>>>(ipw, nqw, ow, fcw, pjw, w_ip);
    mask_pack<<<800, 256, 0, stream>>>(msk, mpk_b);

    u16* w_nq  = w_ip + 1769472;
    u16* w_out = w_nq + 589824;
    u16* w_fc  = w_out + 589824;
    u16* w_pj  = w_fc + 2359296;

    // x = LN1(y) -> bf16
    ln_kernel<<<2856, 256, 0, stream>>>(y, l1g, l1b, x_b, 11424);
    // qkv = x[100:] @ in_proj_w.T + b
    gemm_bt<0, 1, 0><<<dim3(72, 18), 256, 0, stream>>>(x_b + (size_t)3200 * 768, w_ip, ipb, nullptr, qkv_b, 8224, 2304, 768);
    // new_q = x[:100] @ new_q_w.T + b
    gemm_bt<0, 1, 0><<<dim3(32, 6), 256, 0, stream>>>(x_b, w_nq, nqb, nullptr, nq_b, 3200, 768, 768);
    // attention (512 threads / 8 waves per block)
    attn_kernel<<<384, 512, 0, stream>>>(qkv_b, nq_b, mpk_b, ao_b);
    // y2 = y + attn_out @ out_w.T + out_b   -> d_out (f32)
    gemm_bt<0, 0, 1><<<dim3(96, 6), 256, 0, stream>>>(ao_b, w_out, ob, y, out, 11424, 768, 768);
    // h = LN2(y2) -> bf16
    ln_kernel<<<2856, 256, 0, stream>>>(out, l2g, l2b, h_b, 11424);
    // h1 = quickgelu(h @ fc_w.T + fc_b) -> bf16
    gemm_bt<1, 1, 0><<<dim3(96, 24), 256, 0, stream>>>(h_b, w_fc, fcb, nullptr, h1_b, 11424, 3072, 768);
    // out = y2 + h1 @ proj_w.T + proj_b
    gemm_bt<0, 0, 1><<<dim3(96, 6), 256, 0, stream>>>(h1_b, w_pj, pjb, out, out, 11424, 768, 3072);
}